// Round 5
// baseline (1244.054 us; speedup 1.0000x reference)
//
#include <hip/hip_runtime.h>
#include <hip/hip_bf16.h>

// ---------------- constants ----------------
#define Nn_   120000
#define F_    256
#define H_    256
#define L_    64
#define EMP_  1000000
#define E_    200000
#define P0_   60000
#define P1_   80000
#define P2_   100000
#define PROXW 0.3f

typedef __attribute__((ext_vector_type(8))) short bf16x8;
typedef __attribute__((ext_vector_type(4))) float f32x4;

__device__ inline float bf2f(unsigned short u) {
    union { unsigned int i; float f; } x; x.i = ((unsigned int)u) << 16; return x.f;
}
__device__ inline unsigned short f2bf(float f) {
    union { float f; unsigned int i; } x; x.f = f;
    unsigned int r = x.i + 0x7fffu + ((x.i >> 16) & 1u);
    return (unsigned short)(r >> 16);
}
__device__ inline float tanh_fast(float x) {
    float e = __expf(2.0f * x);
    return 1.0f - 2.0f * __builtin_amdgcn_rcpf(e + 1.0f);
}
__device__ inline float sigmoid_fast(float z) {
    return __builtin_amdgcn_rcpf(1.0f + __expf(-z));
}
__device__ inline int lds_off(int row, int s) {
    return row * 64 + ((s ^ ((row >> 1) & 3)) << 4);
}
__device__ inline void gload_lds16(const void* g, void* l) {
    __builtin_amdgcn_global_load_lds((const __attribute__((address_space(1))) void*)g,
                                     (__attribute__((address_space(3))) void*)l, 16, 0, 0);
}
__device__ inline void unpk8(uint4 u, float* o) {
    o[0] = bf2f(u.x & 0xffff); o[1] = bf2f(u.x >> 16);
    o[2] = bf2f(u.y & 0xffff); o[3] = bf2f(u.y >> 16);
    o[4] = bf2f(u.z & 0xffff); o[5] = bf2f(u.z >> 16);
    o[6] = bf2f(u.w & 0xffff); o[7] = bf2f(u.w >> 16);
}

// ---------------- CSR build ----------------
__global__ void k_count(const int* __restrict__ dst, int* __restrict__ cnt, int n) {
    int e = blockIdx.x * 256 + threadIdx.x;
    if (e < n) atomicAdd(&cnt[dst[e]], 1);
}
__global__ void k_block_reduce(const int* __restrict__ cnt, int* __restrict__ bsum, int n) {
    __shared__ int s[256];
    int i = blockIdx.x * 256 + threadIdx.x;
    s[threadIdx.x] = (i < n) ? cnt[i] : 0;
    __syncthreads();
    for (int o = 128; o > 0; o >>= 1) {
        if (threadIdx.x < o) s[threadIdx.x] += s[threadIdx.x + o];
        __syncthreads();
    }
    if (threadIdx.x == 0) bsum[blockIdx.x] = s[0];
}
__global__ void k_scan_bsum(int* bsum, int nb) {
    if (threadIdx.x == 0 && blockIdx.x == 0) {
        int acc = 0;
        for (int i = 0; i < nb; i++) { int v = bsum[i]; bsum[i] = acc; acc += v; }
    }
}
__global__ void k_scan_final(const int* __restrict__ cnt, const int* __restrict__ bsum,
                             int* __restrict__ rowp, int n, int etot) {
    __shared__ int s[256];
    int tid = threadIdx.x;
    int i = blockIdx.x * 256 + tid;
    int v = (i < n) ? cnt[i] : 0;
    s[tid] = v;
    __syncthreads();
    for (int o = 1; o < 256; o <<= 1) {
        int t = 0;
        if (tid >= o) t = s[tid - o];
        __syncthreads();
        s[tid] += t;
        __syncthreads();
    }
    if (i < n) rowp[i] = bsum[blockIdx.x] + s[tid] - v;
    if (i == 0 && blockIdx.x == 0) rowp[n] = etot;
}
__global__ void k_fill(const int* __restrict__ src, const int* __restrict__ dst,
                       const int* __restrict__ rowp, int* __restrict__ fill,
                       int* __restrict__ csr, int n) {
    int e = blockIdx.x * 256 + threadIdx.x;
    if (e < n) {
        int d = dst[e];
        int p = atomicAdd(&fill[d], 1);
        csr[rowp[d] + p] = src[e];
    }
}
__global__ void k_dinv(const int* __restrict__ cnt, float* __restrict__ dinv, int n) {
    int i = blockIdx.x * 256 + threadIdx.x;
    if (i < n) dinv[i] = rsqrtf((float)cnt[i] + 1.0f);
}

// ---------------- small f32 tiled GEMM (256^3 precomputes only) ----------------
#define TM 64
#define TN 64
#define TK 16
template <bool TRANSB>
__global__ void gemm_tiled(const float* __restrict__ A, const float* __restrict__ B,
                           float* __restrict__ C, int M, int K, int N) {
    __shared__ float As[TK][TM + 4];
    __shared__ float Bs[TK][TN + 4];
    int tid = threadIdx.x;
    int tx = tid & 15, ty = tid >> 4;
    int row0 = blockIdx.y * TM, col0 = blockIdx.x * TN;
    int lr = tid >> 2, lc4 = (tid & 3) * 4;
    float acc[4][4] = {};
    for (int k0 = 0; k0 < K; k0 += TK) {
        {
            int gr = row0 + lr;
            float4 v = make_float4(0.f, 0.f, 0.f, 0.f);
            if (gr < M) v = *(const float4*)(A + (size_t)gr * K + k0 + lc4);
            As[lc4 + 0][lr] = v.x; As[lc4 + 1][lr] = v.y;
            As[lc4 + 2][lr] = v.z; As[lc4 + 3][lr] = v.w;
        }
        {
            int n = tid & 63, kk0 = tid >> 6;
#pragma unroll
            for (int p = 0; p < 4; p++) {
                int kk = kk0 + p * 4;
                if (TRANSB) Bs[kk][n] = B[(size_t)(col0 + n) * K + k0 + kk];
                else        Bs[kk][n] = B[(size_t)(k0 + kk) * N + col0 + n];
            }
        }
        __syncthreads();
#pragma unroll
        for (int kk = 0; kk < TK; kk++) {
            float4 a = *(const float4*)&As[kk][ty * 4];
            float4 b = *(const float4*)&Bs[kk][tx * 4];
            float av[4] = {a.x, a.y, a.z, a.w};
            float bv[4] = {b.x, b.y, b.z, b.w};
#pragma unroll
            for (int i = 0; i < 4; i++)
#pragma unroll
                for (int j = 0; j < 4; j++) acc[i][j] += av[i] * bv[j];
        }
        __syncthreads();
    }
#pragma unroll
    for (int i = 0; i < 4; i++) {
        int r = row0 + ty * 4 + i;
        if (r >= M) continue;
#pragma unroll
        for (int j = 0; j < 4; j++) C[(size_t)r * N + col0 + tx * 4 + j] = acc[i][j];
    }
}

// ---------------- conversions / transposes / packs ----------------
__global__ void k_cvt(const float* __restrict__ in, unsigned short* __restrict__ out, int n4) {
    int i = blockIdx.x * 256 + threadIdx.x;
    if (i >= n4) return;
    float4 v = ((const float4*)in)[i];
    ushort4 o;
    o.x = f2bf(v.x); o.y = f2bf(v.y); o.z = f2bf(v.z); o.w = f2bf(v.w);
    ((ushort4*)out)[i] = o;
}
__global__ void k_transpose_cvt(const float* __restrict__ W, unsigned short* __restrict__ Wt,
                                int R, int C) {
    int c = blockIdx.x;
    for (int r = threadIdx.x; r < R; r += 256)
        Wt[(size_t)c * R + r] = f2bf(W[(size_t)r * C + c]);
}
__global__ void k_sym_cvt(const float* __restrict__ W, unsigned short* __restrict__ symb) {
    int r = blockIdx.x, c = threadIdx.x;
    symb[r * 256 + c] = f2bf(0.5f * (W[r * 256 + c] + W[c * 256 + r]));
}
__global__ void k_bt512(const float* __restrict__ linW, const float* __restrict__ W2w,
                        unsigned short* __restrict__ Bt) {
    int idx = blockIdx.x * 256 + threadIdx.x;
    int n = idx >> 9, k = idx & 511;
    float v = (k < 256) ? linW[(size_t)k * 256 + n] : W2w[(size_t)(k - 256) * 256 + n];
    Bt[idx] = f2bf(v);
}
__global__ void k_sumb(const float* __restrict__ b, float* __restrict__ out) {
    __shared__ float s[256];
    int tid = threadIdx.x;
    s[tid] = b[tid];
    __syncthreads();
    for (int o = 128; o > 0; o >>= 1) {
        if (tid < o) s[tid] += s[tid + o];
        __syncthreads();
    }
    if (tid == 0) out[0] = s[0];
}
// Pack Wsrc[512][256] f32 -> P: per (os,ins) a contiguous 1KB chunk, XOR-swizzle baked in.
// Read side: lds_off(row, s) within ins block of 16 rows; n = (ins&15)*16 + lane/4,
// k = (ins>>4)*256 + os*32 + ((lane&3)^((n>>1)&3))*8.
__global__ void k_packB(const float* __restrict__ Wsrc, unsigned short* __restrict__ P) {
    int c = blockIdx.x * 256 + threadIdx.x;          // 16384 chunks
    if (c >= 16384) return;
    int os = c >> 11, r = c & 2047;
    int ins = r >> 6, lane = r & 63;
    int n = ((ins & 15) << 4) + (lane >> 2);
    int kb = ((ins >> 4) << 8) + (os << 5) + (((lane & 3) ^ ((n >> 1) & 3)) << 3);
    bf16x8 v;
#pragma unroll
    for (int j = 0; j < 8; ++j) v[j] = (short)f2bf(Wsrc[(size_t)(kb + j) * 256 + n]);
    *(bf16x8*)(P + (size_t)c * 8) = v;
}

// ---------------- GCN aggregation: one wave per node, 1-deep neighbor prefetch ----------------
__global__ __launch_bounds__(256)
void k_agg_bf(const unsigned short* __restrict__ xw, const int* __restrict__ rowp,
              const int* __restrict__ csr, const float* __restrict__ dinv,
              const float* __restrict__ bias, unsigned short* __restrict__ out) {
    int w = threadIdx.x >> 6, lane = threadIdx.x & 63;
    int v = blockIdx.x * 4 + w;
    if (v >= Nn_) return;
    const uint2* x64 = (const uint2*)xw;
    float a0 = 0.f, a1 = 0.f, a2 = 0.f, a3 = 0.f;
    int beg = rowp[v], end = rowp[v + 1];
    uint2 un = make_uint2(0, 0); float dn = 0.f;
    if (beg < end) {
        int s0 = csr[beg];
        dn = dinv[s0];
        un = x64[(size_t)s0 * 64 + lane];
    }
    for (int p = beg; p < end; ++p) {
        uint2 uc = un; float dc = dn;
        if (p + 1 < end) {
            int s1 = csr[p + 1];
            dn = dinv[s1];
            un = x64[(size_t)s1 * 64 + lane];
        }
        a0 += bf2f(uc.x & 0xffff) * dc;
        a1 += bf2f(uc.x >> 16) * dc;
        a2 += bf2f(uc.y & 0xffff) * dc;
        a3 += bf2f(uc.y >> 16) * dc;
    }
    float dv = dinv[v];
    uint2 us = x64[(size_t)v * 64 + lane];
    a0 = a0 * dv + bf2f(us.x & 0xffff) * dv * dv;
    a1 = a1 * dv + bf2f(us.x >> 16) * dv * dv;
    a2 = a2 * dv + bf2f(us.y & 0xffff) * dv * dv;
    a3 = a3 * dv + bf2f(us.y >> 16) * dv * dv;
    int c0 = lane * 4;
    float4 bv = *(const float4*)(bias + c0);
    uint2 ov;
    ov.x = (unsigned int)f2bf(tanh_fast(a0 + bv.x)) |
           ((unsigned int)f2bf(tanh_fast(a1 + bv.y)) << 16);
    ov.y = (unsigned int)f2bf(tanh_fast(a2 + bv.z)) |
           ((unsigned int)f2bf(tanh_fast(a3 + bv.w)) << 16);
    ((uint2*)out)[(size_t)v * 64 + lane] = ov;
}

// ---------------- MFMA GEMM, dbuf LDS + raw barriers + counted vmcnt ----------------
template <bool BIAS, bool TANH>
__global__ __launch_bounds__(256)
void mfma_gemm(const unsigned short* __restrict__ A0, const unsigned short* __restrict__ A1,
               int Ksplit, int K, const unsigned short* __restrict__ Bt,
               const float* __restrict__ bias, unsigned short* __restrict__ Cb, int M) {
    __shared__ char lds[2][16384];
    int tid = threadIdx.x, lane = tid & 63, w = tid >> 6;
    int row0 = blockIdx.y * 128, col0 = blockIdx.x * 128;
    int wr = w >> 1, wc = w & 1;
    f32x4 acc[4][4] = {};
    int nk = K >> 5;

    auto stage = [&](int ks, int buf) {
        int k0 = ks << 5;
        #pragma unroll
        for (int j = 0; j < 4; ++j) {
            int ins = w + (j << 2);
            int lrow = ((ins & 7) << 4) + (lane >> 2);
            int p = lane & 3;
            int slog = p ^ ((lrow >> 1) & 3);
            char* ldst = lds[buf] + ((ins & 7) << 10) + ((ins >= 8) ? 8192 : 0);
            const unsigned short* src;
            if (ins < 8) {
                int grow = row0 + lrow;
                if (grow >= M) grow = M - 1;
                const unsigned short* Asrc; int kk, pitch;
                if (k0 < Ksplit) { Asrc = A0; kk = k0; pitch = Ksplit; }
                else             { Asrc = A1; kk = k0 - Ksplit; pitch = K - Ksplit; }
                src = Asrc + (size_t)grow * pitch + kk + (slog << 3);
            } else {
                int grow = col0 + lrow;
                src = Bt + (size_t)grow * K + k0 + (slog << 3);
            }
            gload_lds16(src, ldst);
        }
    };

    stage(0, 0);
    for (int ks = 0; ks < nk; ++ks) {
        int cur = ks & 1;
        if (ks + 1 < nk) {
            stage(ks + 1, cur ^ 1);
            asm volatile("s_waitcnt vmcnt(4)" ::: "memory");
        } else {
            asm volatile("s_waitcnt vmcnt(0)" ::: "memory");
        }
        __builtin_amdgcn_s_barrier();
        __builtin_amdgcn_sched_barrier(0);
        int s = lane >> 4, r16 = lane & 15;
        bf16x8 a[4], b[4];
        #pragma unroll
        for (int m = 0; m < 4; ++m) a[m] = *(const bf16x8*)(lds[cur] + lds_off(wr * 64 + m * 16 + r16, s));
        #pragma unroll
        for (int n = 0; n < 4; ++n) b[n] = *(const bf16x8*)(lds[cur] + 8192 + lds_off(wc * 64 + n * 16 + r16, s));
        __builtin_amdgcn_s_setprio(1);
        #pragma unroll
        for (int m = 0; m < 4; ++m)
            #pragma unroll
            for (int n = 0; n < 4; ++n)
                acc[m][n] = __builtin_amdgcn_mfma_f32_16x16x32_bf16(a[m], b[n], acc[m][n], 0, 0, 0);
        __builtin_amdgcn_s_setprio(0);
        __builtin_amdgcn_s_barrier();
        __builtin_amdgcn_sched_barrier(0);
    }
    int q = lane >> 4, r16 = lane & 15;
    float bv[4];
    #pragma unroll
    for (int n = 0; n < 4; ++n) bv[n] = BIAS ? bias[col0 + wc * 64 + n * 16 + r16] : 0.f;
    #pragma unroll
    for (int m = 0; m < 4; ++m) {
        #pragma unroll
        for (int i = 0; i < 4; ++i) {
            int row = row0 + wr * 64 + m * 16 + q * 4 + i;
            if (row >= M) continue;
            #pragma unroll
            for (int n = 0; n < 4; ++n) {
                int col = col0 + wc * 64 + n * 16 + r16;
                float v = acc[m][n][i];
                if (BIAS) v += bv[n];
                if (TANH) v = tanh_fast(v);
                Cb[(size_t)row * 256 + col] = f2bf(v);
            }
        }
    }
}

// ---------------- attention u: 16 lanes/node, online softmax ----------------
__global__ __launch_bounds__(256)
void k_attn_u2(const unsigned short* __restrict__ emb, const unsigned short* __restrict__ t,
               const float* __restrict__ p0, const float* __restrict__ p1,
               const float* __restrict__ p2, unsigned short* __restrict__ u) {
    int tid = threadIdx.x;
    int g = tid >> 4, l = tid & 15;
    int n = blockIdx.x * 16 + g;
    size_t eoff = (size_t)n * 256 + l * 16;
    const uint4* e16 = (const uint4*)(emb + eoff);
    uint4* u16 = (uint4*)(u + eoff);
    uint4 eb0 = e16[0], eb1 = e16[1];
    if (n >= P2_) { u16[0] = eb0; u16[1] = eb1; return; }
    float tv[16], ev[16];
    {
        const uint4* t16 = (const uint4*)(t + eoff);
        unpk8(t16[0], tv); unpk8(t16[1], tv + 8);
        unpk8(eb0, ev); unpk8(eb1, ev + 8);
    }
    float m = -3.0e38f, den = 0.f, o[16];
    #pragma unroll
    for (int i = 0; i < 16; i++) o[i] = 0.f;
    auto accum = [&](const float* sv) {
        float dt = 0.f;
        #pragma unroll
        for (int i = 0; i < 16; i++) dt += tv[i] * sv[i];
        dt += __shfl_xor(dt, 1);
        dt += __shfl_xor(dt, 2);
        dt += __shfl_xor(dt, 4);
        dt += __shfl_xor(dt, 8);
        float lg = dt * 0.0625f;
        float mn = fmaxf(m, lg);
        float s0 = __expf(m - mn), s1 = __expf(lg - mn);
        den = den * s0 + s1;
        #pragma unroll
        for (int i = 0; i < 16; i++) o[i] = o[i] * s0 + s1 * sv[i];
        m = mn;
    };
    auto accum_f32 = [&](const float* base) {
        float sv[16];
        const float4* b4 = (const float4*)(base + eoff);
        #pragma unroll
        for (int i = 0; i < 4; i++) {
            float4 q = b4[i];
            sv[4 * i] = q.x; sv[4 * i + 1] = q.y; sv[4 * i + 2] = q.z; sv[4 * i + 3] = q.w;
        }
        accum(sv);
    };
    if (n < P0_)      { accum_f32(p0); accum_f32(p1); accum_f32(p2); }
    else if (n < P1_) { accum_f32(p1); accum_f32(p2); }
    else              { accum_f32(p2); }
    accum(ev);
    float inv = __builtin_amdgcn_rcpf(den);
    unsigned short h[16];
    #pragma unroll
    for (int i = 0; i < 16; i++) h[i] = f2bf(o[i] * inv);
    uint4 r0, r1;
    r0.x = h[0] | ((unsigned int)h[1] << 16);  r0.y = h[2] | ((unsigned int)h[3] << 16);
    r0.z = h[4] | ((unsigned int)h[5] << 16);  r0.w = h[6] | ((unsigned int)h[7] << 16);
    r1.x = h[8] | ((unsigned int)h[9] << 16);  r1.y = h[10] | ((unsigned int)h[11] << 16);
    r1.z = h[12] | ((unsigned int)h[13] << 16); r1.w = h[14] | ((unsigned int)h[15] << 16);
    u16[0] = r0; u16[1] = r1;
}

// ---------------- fused edge MLP v2: 512 thr, 128 edges/block, packed B, raw barriers ----------------
template <bool SIM>
__global__ __launch_bounds__(512, 4)
void mfma_edge2(const unsigned short* __restrict__ srcemb, const unsigned short* __restrict__ gsrc,
                const int* __restrict__ es, const int* __restrict__ ed,
                const unsigned short* __restrict__ Pk, const float* __restrict__ b1,
                const float* __restrict__ w2, const float* __restrict__ sumb,
                float* __restrict__ a_pre, float* __restrict__ mlsc) {
    __shared__ char lds[16384 + 32768];   // A: 2 tiles x (mean 4K | max 4K); B: 32K
    __shared__ float red[128];
    int tid = threadIdx.x, lane = tid & 63, w = tid >> 6;
    int e0 = blockIdx.x * 128;
    int arow = tid >> 2, p = tid & 3;     // arow 0..127 (edge within block)
    int erow = e0 + arow;
    int ec = (erow < E_) ? erow : (E_ - 1);
    int ia = es[ec], ib = ed[ec];
    const unsigned short* ra = srcemb + (size_t)ia * 256;
    const unsigned short* rb = srcemb + (size_t)ib * 256;
    const unsigned short* rg = SIM ? (gsrc + (size_t)ia * 256) : nullptr;
    int slog = p ^ ((arow >> 1) & 3);
    int abase = ((arow >> 6) << 13) + ((arow & 63) << 6) + (p << 4);
    if (tid < 128) red[tid] = 0.f;
    float simacc = 0.f;
    f32x4 acc[4][4] = {};
    // prologue: prefetch step-0 A slices
    uint4 pa = *(const uint4*)(ra + (slog << 3));
    uint4 pb = *(const uint4*)(rb + (slog << 3));
    uint4 pg = make_uint4(0, 0, 0, 0);
    if (SIM) pg = *(const uint4*)(rg + (slog << 3));
    #pragma unroll
    for (int os = 0; os < 8; ++os) {
        // A convert + swizzled ds_write (compiler waits on pa/pb/pg)
        {
            float fa[8], fb[8];
            unpk8(pa, fa); unpk8(pb, fb);
            bf16x8 vm, vx;
            #pragma unroll
            for (int i = 0; i < 8; i++) {
                vm[i] = (short)f2bf(0.5f * (fa[i] + fb[i]));
                vx[i] = (short)f2bf(fmaxf(fa[i], fb[i]));
            }
            *(bf16x8*)(lds + abase) = vm;
            *(bf16x8*)(lds + 4096 + abase) = vx;
            if (SIM) {
                float fg[8];
                unpk8(pg, fg);
                #pragma unroll
                for (int i = 0; i < 8; i++) simacc += fg[i] * fb[i];
            }
        }
        // B stage: 32 linear 1KB chunks from packed Pk (4 per wave)
        #pragma unroll
        for (int j = 0; j < 4; ++j) {
            int ins = (j << 3) + w;
            const unsigned short* src = Pk + ((os * 32 + ins) << 9) + (lane << 3);
            gload_lds16(src, lds + 16384 + (ins << 10));
        }
        // A prefetch for step os+1 (stays in flight across barrier + MFMA)
        if (os < 7) {
            int cb = ((os + 1) << 5) + (slog << 3);
            pa = *(const uint4*)(ra + cb);
            pb = *(const uint4*)(rb + cb);
            if (SIM) {
                pg = *(const uint4*)(rg + cb);
                asm volatile("s_waitcnt vmcnt(3) lgkmcnt(0)" ::: "memory");
            } else {
                asm volatile("s_waitcnt vmcnt(2) lgkmcnt(0)" ::: "memory");
            }
        } else {
            asm volatile("s_waitcnt vmcnt(0) lgkmcnt(0)" ::: "memory");
        }
        __builtin_amdgcn_s_barrier();
        __builtin_amdgcn_sched_barrier(0);
        int s = lane >> 4, r16 = lane & 15;
        int ta = (w >> 2) << 13;     // tile A base
        int qn = (w & 3) << 6;       // N-quadrant base
        #pragma unroll
        for (int half = 0; half < 2; ++half) {
            bf16x8 a[4], b[4];
            #pragma unroll
            for (int m2 = 0; m2 < 4; ++m2)
                a[m2] = *(const bf16x8*)(lds + ta + half * 4096 + lds_off(m2 * 16 + r16, s));
            #pragma unroll
            for (int n2 = 0; n2 < 4; ++n2)
                b[n2] = *(const bf16x8*)(lds + 16384 + half * 16384 + lds_off(qn + n2 * 16 + r16, s));
            __builtin_amdgcn_s_setprio(1);
            #pragma unroll
            for (int m2 = 0; m2 < 4; ++m2)
                #pragma unroll
                for (int n2 = 0; n2 < 4; ++n2)
                    acc[m2][n2] = __builtin_amdgcn_mfma_f32_16x16x32_bf16(a[m2], b[n2], acc[m2][n2], 0, 0, 0);
            __builtin_amdgcn_s_setprio(0);
        }
        __builtin_amdgcn_s_barrier();
        __builtin_amdgcn_sched_barrier(0);
    }
    // epilogue: layer-2 dot, reduce to per-edge scalar
    int q = lane >> 4, r16 = lane & 15;
    float b1c[4], w2c[4];
    #pragma unroll
    for (int n2 = 0; n2 < 4; ++n2) {
        int c = ((w & 3) << 6) + n2 * 16 + r16;
        b1c[n2] = b1[c]; w2c[n2] = w2[c];
    }
    #pragma unroll
    for (int m2 = 0; m2 < 4; ++m2) {
        #pragma unroll
        for (int i = 0; i < 4; ++i) {
            int row = ((w >> 2) << 6) + m2 * 16 + q * 4 + i;
            float ps = 0.f;
            #pragma unroll
            for (int n2 = 0; n2 < 4; ++n2) ps += tanh_fast(acc[m2][n2][i] + b1c[n2]) * w2c[n2];
            ps += __shfl_xor(ps, 1);
            ps += __shfl_xor(ps, 2);
            ps += __shfl_xor(ps, 4);
            ps += __shfl_xor(ps, 8);
            if (r16 == 0) atomicAdd(&red[row], ps);
        }
    }
    if (SIM) {
        simacc += __shfl_xor(simacc, 1);
        simacc += __shfl_xor(simacc, 2);
        if (p == 0 && erow < E_) mlsc[erow] = sigmoid_fast(simacc + sumb[0]);
    }
    __syncthreads();
    if (tid < 128 && e0 + tid < E_) a_pre[e0 + tid] = red[tid];
}

// ---------------- final ensemble ----------------
__global__ void k_final(const float* __restrict__ apml, const float* __restrict__ apms,
                        const float* __restrict__ mlsc, const float* __restrict__ mstr,
                        const float* __restrict__ pxtr, const int* __restrict__ index,
                        const float* __restrict__ mlb2, const float* __restrict__ msb2,
                        float* __restrict__ out) {
    int e = blockIdx.x * 256 + threadIdx.x;
    if (e >= E_) return;
    float aml = tanh_fast(apml[e] + mlb2[0]);
    float ams = tanh_fast(apms[e] + msb2[0]);
    float apx = PROXW;
    float m = fmaxf(aml, fmaxf(ams, apx));
    float wml = __expf(aml - m), wms = __expf(ams - m), wpx = __expf(apx - m);
    float inv = __builtin_amdgcn_rcpf(wml + wms + wpx);
    int idx = index[e];
    float v = (mlsc[e] * wml + mstr[idx] * wms + pxtr[idx] * wpx) * inv;
    out[e] = fminf(fmaxf(v, 0.f), 1.f);
}

__global__ void k_sentinel(float* out, int n) {
    int i = blockIdx.x * 256 + threadIdx.x;
    if (i < n) out[i] = -12345.0f;
}

// ---------------- launch ----------------
extern "C" void kernel_launch(void* const* d_in, const int* in_sizes, int n_in,
                              void* d_out, int out_size, void* d_ws, size_t ws_size,
                              hipStream_t stream) {
    const float* x     = (const float*)d_in[0];
    const int*   mp    = (const int*)d_in[1];
    const int*   edges = (const int*)d_in[2];
    const int*   index = (const int*)d_in[3];
    const float* p0    = (const float*)d_in[4];
    const float* p1    = (const float*)d_in[5];
    const float* p2    = (const float*)d_in[6];
    const float* gc1W  = (const float*)d_in[7];
    const float* gc1b  = (const float*)d_in[8];
    const float* gc2W  = (const float*)d_in[9];
    const float* gc2b  = (const float*)d_in[10];
    const float* linW  = (const float*)d_in[11];
    const float* linb  = (const float*)d_in[12];
    const float* wlin  = (const float*)d_in[13];
    const float* blin  = (const float*)d_in[14];
    const float* wq    = (const float*)d_in[15];
    const float* wk    = (const float*)d_in[16];
    const float* wv    = (const float*)d_in[17];
    const float* mlw1  = (const float*)d_in[18];
    const float* mlb1  = (const float*)d_in[19];
    const float* mlw2  = (const float*)d_in[20];
    const float* mlb2  = (const float*)d_in[21];
    const float* msw1  = (const float*)d_in[22];
    const float* msb1  = (const float*)d_in[23];
    const float* msw2  = (const float*)d_in[24];
    const float* msb2  = (const float*)d_in[25];
    const float* msdrW = (const float*)d_in[26];
    const float* msdrb = (const float*)d_in[27];
    const float* logits = (const float*)d_in[28];
    const float* mstr  = (const float*)d_in[29];
    const float* pxtr  = (const float*)d_in[30];
    float* out = (float*)d_out;

    const int* src_mp = mp;
    const int* dst_mp = mp + EMP_;
    const int* es = edges;
    const int* ed = edges + E_;

    char* ws = (char*)d_ws;
    size_t off = 0;
    auto alloc = [&](size_t bytes) -> char* {
        off = (off + 255) & ~(size_t)255;
        char* r = ws + off;
        off += bytes;
        return r;
    };
    const size_t NODE_BF = (size_t)Nn_ * 256 * 2;
    unsigned short* W0 = (unsigned short*)alloc(NODE_BF);  // xb -> gb
    unsigned short* W1 = (unsigned short*)alloc(NODE_BF);  // xw1/xw2 -> logitsb
    unsigned short* W2 = (unsigned short*)alloc(NODE_BF);  // hb -> rb
    unsigned short* W3 = (unsigned short*)alloc(NODE_BF);  // embb
    unsigned short* W4 = (unsigned short*)alloc(NODE_BF);  // tb/ub
    unsigned short* W5 = (unsigned short*)alloc(NODE_BF);  // emb2b
    int*   cnt  = (int*)alloc((size_t)Nn_ * 4);
    int*   rowp = (int*)alloc((size_t)(Nn_ + 1) * 4);
    int*   fill = (int*)alloc((size_t)Nn_ * 4);
    int*   csr  = (int*)alloc((size_t)EMP_ * 4);
    float* dinv = (float*)alloc((size_t)Nn_ * 4);
    int*   bsum = (int*)alloc(512 * 4);
    float* Mqk  = (float*)alloc(65536 * 4);
    float* W2wf = (float*)alloc(65536 * 4);
    unsigned short* gc1Wt = (unsigned short*)alloc(65536 * 2);
    unsigned short* gc2Wt = (unsigned short*)alloc(65536 * 2);
    unsigned short* MqkT  = (unsigned short*)alloc(65536 * 2);
    unsigned short* Bt512 = (unsigned short*)alloc(131072 * 2);
    unsigned short* symb  = (unsigned short*)alloc(65536 * 2);
    unsigned short* msdrWt = (unsigned short*)alloc(16384 * 2);
    unsigned short* mlPk  = (unsigned short*)alloc(131072 * 2);
    unsigned short* msPk  = (unsigned short*)alloc(131072 * 2);
    float* apml = (float*)alloc((size_t)E_ * 4);
    float* apms = (float*)alloc((size_t)E_ * 4);
    float* mlsc = (float*)alloc((size_t)E_ * 4);
    float* sumb = (float*)alloc(256);

    if (off > ws_size) {
        k_sentinel<<<(E_ + 255) / 256, 256, 0, stream>>>(out, E_);
        return;
    }

    hipMemsetAsync(cnt, 0, (size_t)Nn_ * 4, stream);
    hipMemsetAsync(fill, 0, (size_t)Nn_ * 4, stream);

    const int NB = (Nn_ + 255) / 256;
    const int EB = (EMP_ + 255) / 256;

    // input conversions + weight prep
    k_cvt<<<30000, 256, 0, stream>>>(x, W0, Nn_ * 256 / 4);
    k_transpose_cvt<<<256, 256, 0, stream>>>(gc1W, gc1Wt, 256, 256);
    k_transpose_cvt<<<256, 256, 0, stream>>>(gc2W, gc2Wt, 256, 256);
    k_transpose_cvt<<<256, 256, 0, stream>>>(msdrW, msdrWt, 64, 256);
    k_packB<<<64, 256, 0, stream>>>(mlw1, mlPk);
    k_packB<<<64, 256, 0, stream>>>(msw1, msPk);
    k_sym_cvt<<<256, 256, 0, stream>>>(wlin, symb);
    k_sumb<<<1, 256, 0, stream>>>(blin, sumb);
    dim3 gSmall(4, 4);
    gemm_tiled<true><<<gSmall, 256, 0, stream>>>(wq, wk, Mqk, 256, 256, 256);
    gemm_tiled<false><<<gSmall, 256, 0, stream>>>(wv, linW + 256 * 256, W2wf, 256, 256, 256);
    k_transpose_cvt<<<256, 256, 0, stream>>>(Mqk, MqkT, 256, 256);
    k_bt512<<<512, 256, 0, stream>>>(linW, W2wf, Bt512);

    // CSR
    k_count<<<EB, 256, 0, stream>>>(dst_mp, cnt, EMP_);
    k_block_reduce<<<NB, 256, 0, stream>>>(cnt, bsum, Nn_);
    k_scan_bsum<<<1, 64, 0, stream>>>(bsum, NB);
    k_scan_final<<<NB, 256, 0, stream>>>(cnt, bsum, rowp, Nn_, EMP_);
    k_fill<<<EB, 256, 0, stream>>>(src_mp, dst_mp, rowp, fill, csr, EMP_);
    k_dinv<<<NB, 256, 0, stream>>>(cnt, dinv, Nn_);

    dim3 gFull(2, (Nn_ + 127) / 128);
    dim3 gT(2, (P2_ + 127) / 128);
    const int AGG_B = (Nn_ + 3) / 4;

    // GCN layer 1
    mfma_gemm<false, false><<<gFull, 256, 0, stream>>>(W0, W0, 256, 256, gc1Wt, nullptr, W1, Nn_);
    k_agg_bf<<<AGG_B, 256, 0, stream>>>(W1, rowp, csr, dinv, gc1b, W2);
    // GCN layer 2
    mfma_gemm<false, false><<<gFull, 256, 0, stream>>>(W2, W2, 256, 256, gc2Wt, nullptr, W1, Nn_);
    k_agg_bf<<<AGG_B, 256, 0, stream>>>(W1, rowp, csr, dinv, gc2b, W3);

    // attention: t = emb @ Mqk (rows < P2), then u (16 nodes/block)
    mfma_gemm<false, false><<<gT, 256, 0, stream>>>(W3, W3, 256, 256, MqkT, nullptr, W4, P2_);
    k_attn_u2<<<Nn_ / 16, 256, 0, stream>>>(W3, W4, p0, p1, p2, W4);

    // emb2 = tanh([emb|u] @ Bt512^T + linb)
    mfma_gemm<true, true><<<gFull, 256, 0, stream>>>(W3, W4, 256, 512, Bt512, linb, W5, Nn_);

    // g = emb2 @ sym
    mfma_gemm<false, false><<<gFull, 256, 0, stream>>>(W5, W5, 256, 256, symb, nullptr, W0, Nn_);

    // r = tanh(logits @ msdrW + msdrb)
    k_cvt<<<7500, 256, 0, stream>>>(logits, W1, Nn_ * 64 / 4);
    mfma_gemm<true, true><<<gFull, 256, 0, stream>>>(W1, W1, 64, 64, msdrWt, msdrb, W2, Nn_);

    // edge MLPs (+fused bilinear sim in the ml pass)
    const int EB2 = (E_ + 127) / 128;   // 1563
    mfma_edge2<true><<<EB2, 512, 0, stream>>>(W5, W0, es, ed, mlPk, mlb1, mlw2, sumb, apml, mlsc);
    mfma_edge2<false><<<EB2, 512, 0, stream>>>(W2, nullptr, es, ed, msPk, msb1, msw2, sumb, apms, nullptr);

    // final ensemble
    k_final<<<(E_ + 255) / 256, 256, 0, stream>>>(apml, apms, mlsc, mstr, pxtr, index, mlb2, msb2, out);
}

// Round 6
// 1009.549 us; speedup vs baseline: 1.2323x; 1.2323x over previous
//
#include <hip/hip_runtime.h>
#include <hip/hip_bf16.h>

// ---------------- constants ----------------
#define Nn_   120000
#define F_    256
#define H_    256
#define L_    64
#define EMP_  1000000
#define E_    200000
#define P0_   60000
#define P1_   80000
#define P2_   100000
#define PROXW 0.3f

typedef __attribute__((ext_vector_type(8))) short bf16x8;
typedef __attribute__((ext_vector_type(4))) float f32x4;

__device__ inline float bf2f(unsigned short u) {
    union { unsigned int i; float f; } x; x.i = ((unsigned int)u) << 16; return x.f;
}
__device__ inline unsigned short f2bf(float f) {
    union { float f; unsigned int i; } x; x.f = f;
    unsigned int r = x.i + 0x7fffu + ((x.i >> 16) & 1u);
    return (unsigned short)(r >> 16);
}
__device__ inline float tanh_fast(float x) {
    float e = __expf(2.0f * x);
    return 1.0f - 2.0f * __builtin_amdgcn_rcpf(e + 1.0f);
}
__device__ inline float sigmoid_fast(float z) {
    return __builtin_amdgcn_rcpf(1.0f + __expf(-z));
}
__device__ inline int lds_off(int row, int s) {
    return row * 64 + ((s ^ ((row >> 1) & 3)) << 4);
}
__device__ inline void gload_lds16(const void* g, void* l) {
    __builtin_amdgcn_global_load_lds((const __attribute__((address_space(1))) void*)g,
                                     (__attribute__((address_space(3))) void*)l, 16, 0, 0);
}
__device__ inline void unpk8(uint4 u, float* o) {
    o[0] = bf2f(u.x & 0xffff); o[1] = bf2f(u.x >> 16);
    o[2] = bf2f(u.y & 0xffff); o[3] = bf2f(u.y >> 16);
    o[4] = bf2f(u.z & 0xffff); o[5] = bf2f(u.z >> 16);
    o[6] = bf2f(u.w & 0xffff); o[7] = bf2f(u.w >> 16);
}

// ---------------- CSR build ----------------
__global__ void k_count(const int* __restrict__ dst, int* __restrict__ cnt, int n) {
    int e = blockIdx.x * 256 + threadIdx.x;
    if (e < n) atomicAdd(&cnt[dst[e]], 1);
}
__global__ void k_block_reduce(const int* __restrict__ cnt, int* __restrict__ bsum, int n) {
    __shared__ int s[256];
    int i = blockIdx.x * 256 + threadIdx.x;
    s[threadIdx.x] = (i < n) ? cnt[i] : 0;
    __syncthreads();
    for (int o = 128; o > 0; o >>= 1) {
        if (threadIdx.x < o) s[threadIdx.x] += s[threadIdx.x + o];
        __syncthreads();
    }
    if (threadIdx.x == 0) bsum[blockIdx.x] = s[0];
}
__global__ void k_scan_bsum(int* bsum, int nb) {
    if (threadIdx.x == 0 && blockIdx.x == 0) {
        int acc = 0;
        for (int i = 0; i < nb; i++) { int v = bsum[i]; bsum[i] = acc; acc += v; }
    }
}
__global__ void k_scan_final(const int* __restrict__ cnt, const int* __restrict__ bsum,
                             int* __restrict__ rowp, int n, int etot) {
    __shared__ int s[256];
    int tid = threadIdx.x;
    int i = blockIdx.x * 256 + tid;
    int v = (i < n) ? cnt[i] : 0;
    s[tid] = v;
    __syncthreads();
    for (int o = 1; o < 256; o <<= 1) {
        int t = 0;
        if (tid >= o) t = s[tid - o];
        __syncthreads();
        s[tid] += t;
        __syncthreads();
    }
    if (i < n) rowp[i] = bsum[blockIdx.x] + s[tid] - v;
    if (i == 0 && blockIdx.x == 0) rowp[n] = etot;
}
__global__ void k_fill(const int* __restrict__ src, const int* __restrict__ dst,
                       const int* __restrict__ rowp, int* __restrict__ fill,
                       int* __restrict__ csr, int n) {
    int e = blockIdx.x * 256 + threadIdx.x;
    if (e < n) {
        int d = dst[e];
        int p = atomicAdd(&fill[d], 1);
        csr[rowp[d] + p] = src[e];
    }
}
__global__ void k_dinv(const int* __restrict__ cnt, float* __restrict__ dinv, int n) {
    int i = blockIdx.x * 256 + threadIdx.x;
    if (i < n) dinv[i] = rsqrtf((float)cnt[i] + 1.0f);
}

// ---------------- small f32 tiled GEMM (256^3 precomputes only) ----------------
#define TM 64
#define TN 64
#define TK 16
template <bool TRANSB>
__global__ void gemm_tiled(const float* __restrict__ A, const float* __restrict__ B,
                           float* __restrict__ C, int M, int K, int N) {
    __shared__ float As[TK][TM + 4];
    __shared__ float Bs[TK][TN + 4];
    int tid = threadIdx.x;
    int tx = tid & 15, ty = tid >> 4;
    int row0 = blockIdx.y * TM, col0 = blockIdx.x * TN;
    int lr = tid >> 2, lc4 = (tid & 3) * 4;
    float acc[4][4] = {};
    for (int k0 = 0; k0 < K; k0 += TK) {
        {
            int gr = row0 + lr;
            float4 v = make_float4(0.f, 0.f, 0.f, 0.f);
            if (gr < M) v = *(const float4*)(A + (size_t)gr * K + k0 + lc4);
            As[lc4 + 0][lr] = v.x; As[lc4 + 1][lr] = v.y;
            As[lc4 + 2][lr] = v.z; As[lc4 + 3][lr] = v.w;
        }
        {
            int n = tid & 63, kk0 = tid >> 6;
#pragma unroll
            for (int p = 0; p < 4; p++) {
                int kk = kk0 + p * 4;
                if (TRANSB) Bs[kk][n] = B[(size_t)(col0 + n) * K + k0 + kk];
                else        Bs[kk][n] = B[(size_t)(k0 + kk) * N + col0 + n];
            }
        }
        __syncthreads();
#pragma unroll
        for (int kk = 0; kk < TK; kk++) {
            float4 a = *(const float4*)&As[kk][ty * 4];
            float4 b = *(const float4*)&Bs[kk][tx * 4];
            float av[4] = {a.x, a.y, a.z, a.w};
            float bv[4] = {b.x, b.y, b.z, b.w};
#pragma unroll
            for (int i = 0; i < 4; i++)
#pragma unroll
                for (int j = 0; j < 4; j++) acc[i][j] += av[i] * bv[j];
        }
        __syncthreads();
    }
#pragma unroll
    for (int i = 0; i < 4; i++) {
        int r = row0 + ty * 4 + i;
        if (r >= M) continue;
#pragma unroll
        for (int j = 0; j < 4; j++) C[(size_t)r * N + col0 + tx * 4 + j] = acc[i][j];
    }
}

// ---------------- conversions / transposes / packs ----------------
__global__ void k_cvt(const float* __restrict__ in, unsigned short* __restrict__ out, int n4) {
    int i = blockIdx.x * 256 + threadIdx.x;
    if (i >= n4) return;
    float4 v = ((const float4*)in)[i];
    ushort4 o;
    o.x = f2bf(v.x); o.y = f2bf(v.y); o.z = f2bf(v.z); o.w = f2bf(v.w);
    ((ushort4*)out)[i] = o;
}
__global__ void k_transpose_cvt(const float* __restrict__ W, unsigned short* __restrict__ Wt,
                                int R, int C) {
    int c = blockIdx.x;
    for (int r = threadIdx.x; r < R; r += 256)
        Wt[(size_t)c * R + r] = f2bf(W[(size_t)r * C + c]);
}
__global__ void k_sym_cvt(const float* __restrict__ W, unsigned short* __restrict__ symb) {
    int r = blockIdx.x, c = threadIdx.x;
    symb[r * 256 + c] = f2bf(0.5f * (W[r * 256 + c] + W[c * 256 + r]));
}
__global__ void k_bt512(const float* __restrict__ linW, const float* __restrict__ W2w,
                        unsigned short* __restrict__ Bt) {
    int idx = blockIdx.x * 256 + threadIdx.x;
    int n = idx >> 9, k = idx & 511;
    float v = (k < 256) ? linW[(size_t)k * 256 + n] : W2w[(size_t)(k - 256) * 256 + n];
    Bt[idx] = f2bf(v);
}
__global__ void k_sumb(const float* __restrict__ b, float* __restrict__ out) {
    __shared__ float s[256];
    int tid = threadIdx.x;
    s[tid] = b[tid];
    __syncthreads();
    for (int o = 128; o > 0; o >>= 1) {
        if (tid < o) s[tid] += s[tid + o];
        __syncthreads();
    }
    if (tid == 0) out[0] = s[0];
}
// Pack Wsrc[512][256] f32 -> fragment layout: chunk c = (os*2+half)*16 + colb (0..255),
// lane l holds 8 bf16 at col = colb*16 + (l&15), k = half*256 + os*32 + (l>>4)*8.
__global__ void k_packBF(const float* __restrict__ Wsrc, unsigned short* __restrict__ P) {
    int t = blockIdx.x * 256 + threadIdx.x;   // 0..16383 (chunk, lane)
    if (t >= 16384) return;
    int c = t >> 6, l = t & 63;
    int os = c >> 5, half = (c >> 4) & 1, colb = c & 15;
    int col = (colb << 4) + (l & 15);
    int k = (half << 8) + (os << 5) + ((l >> 4) << 3);
    bf16x8 v;
#pragma unroll
    for (int j = 0; j < 8; ++j) v[j] = (short)f2bf(Wsrc[(size_t)(k + j) * 256 + col]);
    *(bf16x8*)(P + (size_t)t * 8) = v;
}

// ---------------- GCN aggregation: one wave per node, 1-deep neighbor prefetch ----------------
__global__ __launch_bounds__(256)
void k_agg_bf(const unsigned short* __restrict__ xw, const int* __restrict__ rowp,
              const int* __restrict__ csr, const float* __restrict__ dinv,
              const float* __restrict__ bias, unsigned short* __restrict__ out) {
    int w = threadIdx.x >> 6, lane = threadIdx.x & 63;
    int v = blockIdx.x * 4 + w;
    if (v >= Nn_) return;
    const uint2* x64 = (const uint2*)xw;
    float a0 = 0.f, a1 = 0.f, a2 = 0.f, a3 = 0.f;
    int beg = rowp[v], end = rowp[v + 1];
    uint2 un = make_uint2(0, 0); float dn = 0.f;
    if (beg < end) {
        int s0 = csr[beg];
        dn = dinv[s0];
        un = x64[(size_t)s0 * 64 + lane];
    }
    for (int p = beg; p < end; ++p) {
        uint2 uc = un; float dc = dn;
        if (p + 1 < end) {
            int s1 = csr[p + 1];
            dn = dinv[s1];
            un = x64[(size_t)s1 * 64 + lane];
        }
        a0 += bf2f(uc.x & 0xffff) * dc;
        a1 += bf2f(uc.x >> 16) * dc;
        a2 += bf2f(uc.y & 0xffff) * dc;
        a3 += bf2f(uc.y >> 16) * dc;
    }
    float dv = dinv[v];
    uint2 us = x64[(size_t)v * 64 + lane];
    a0 = a0 * dv + bf2f(us.x & 0xffff) * dv * dv;
    a1 = a1 * dv + bf2f(us.x >> 16) * dv * dv;
    a2 = a2 * dv + bf2f(us.y & 0xffff) * dv * dv;
    a3 = a3 * dv + bf2f(us.y >> 16) * dv * dv;
    int c0 = lane * 4;
    float4 bv = *(const float4*)(bias + c0);
    uint2 ov;
    ov.x = (unsigned int)f2bf(tanh_fast(a0 + bv.x)) |
           ((unsigned int)f2bf(tanh_fast(a1 + bv.y)) << 16);
    ov.y = (unsigned int)f2bf(tanh_fast(a2 + bv.z)) |
           ((unsigned int)f2bf(tanh_fast(a3 + bv.w)) << 16);
    ((uint2*)out)[(size_t)v * 64 + lane] = ov;
}

// ---------------- MFMA GEMM, dbuf LDS + raw barriers + counted vmcnt ----------------
template <bool BIAS, bool TANH>
__global__ __launch_bounds__(256)
void mfma_gemm(const unsigned short* __restrict__ A0, const unsigned short* __restrict__ A1,
               int Ksplit, int K, const unsigned short* __restrict__ Bt,
               const float* __restrict__ bias, unsigned short* __restrict__ Cb, int M) {
    __shared__ char lds[2][16384];
    int tid = threadIdx.x, lane = tid & 63, w = tid >> 6;
    int row0 = blockIdx.y * 128, col0 = blockIdx.x * 128;
    int wr = w >> 1, wc = w & 1;
    f32x4 acc[4][4] = {};
    int nk = K >> 5;

    auto stage = [&](int ks, int buf) {
        int k0 = ks << 5;
        #pragma unroll
        for (int j = 0; j < 4; ++j) {
            int ins = w + (j << 2);
            int lrow = ((ins & 7) << 4) + (lane >> 2);
            int p = lane & 3;
            int slog = p ^ ((lrow >> 1) & 3);
            char* ldst = lds[buf] + ((ins & 7) << 10) + ((ins >= 8) ? 8192 : 0);
            const unsigned short* src;
            if (ins < 8) {
                int grow = row0 + lrow;
                if (grow >= M) grow = M - 1;
                const unsigned short* Asrc; int kk, pitch;
                if (k0 < Ksplit) { Asrc = A0; kk = k0; pitch = Ksplit; }
                else             { Asrc = A1; kk = k0 - Ksplit; pitch = K - Ksplit; }
                src = Asrc + (size_t)grow * pitch + kk + (slog << 3);
            } else {
                int grow = col0 + lrow;
                src = Bt + (size_t)grow * K + k0 + (slog << 3);
            }
            gload_lds16(src, ldst);
        }
    };

    stage(0, 0);
    for (int ks = 0; ks < nk; ++ks) {
        int cur = ks & 1;
        if (ks + 1 < nk) {
            stage(ks + 1, cur ^ 1);
            asm volatile("s_waitcnt vmcnt(4)" ::: "memory");
        } else {
            asm volatile("s_waitcnt vmcnt(0)" ::: "memory");
        }
        __builtin_amdgcn_s_barrier();
        __builtin_amdgcn_sched_barrier(0);
        int s = lane >> 4, r16 = lane & 15;
        bf16x8 a[4], b[4];
        #pragma unroll
        for (int m = 0; m < 4; ++m) a[m] = *(const bf16x8*)(lds[cur] + lds_off(wr * 64 + m * 16 + r16, s));
        #pragma unroll
        for (int n = 0; n < 4; ++n) b[n] = *(const bf16x8*)(lds[cur] + 8192 + lds_off(wc * 64 + n * 16 + r16, s));
        __builtin_amdgcn_s_setprio(1);
        #pragma unroll
        for (int m = 0; m < 4; ++m)
            #pragma unroll
            for (int n = 0; n < 4; ++n)
                acc[m][n] = __builtin_amdgcn_mfma_f32_16x16x32_bf16(a[m], b[n], acc[m][n], 0, 0, 0);
        __builtin_amdgcn_s_setprio(0);
        __builtin_amdgcn_s_barrier();
        __builtin_amdgcn_sched_barrier(0);
    }
    int q = lane >> 4, r16 = lane & 15;
    float bv[4];
    #pragma unroll
    for (int n = 0; n < 4; ++n) bv[n] = BIAS ? bias[col0 + wc * 64 + n * 16 + r16] : 0.f;
    #pragma unroll
    for (int m = 0; m < 4; ++m) {
        #pragma unroll
        for (int i = 0; i < 4; ++i) {
            int row = row0 + wr * 64 + m * 16 + q * 4 + i;
            if (row >= M) continue;
            #pragma unroll
            for (int n = 0; n < 4; ++n) {
                int col = col0 + wc * 64 + n * 16 + r16;
                float v = acc[m][n][i];
                if (BIAS) v += bv[n];
                if (TANH) v = tanh_fast(v);
                Cb[(size_t)row * 256 + col] = f2bf(v);
            }
        }
    }
}

// ---------------- attention u: 16 lanes/node, online softmax ----------------
__global__ __launch_bounds__(256)
void k_attn_u2(const unsigned short* __restrict__ emb, const unsigned short* __restrict__ t,
               const float* __restrict__ p0, const float* __restrict__ p1,
               const float* __restrict__ p2, unsigned short* __restrict__ u) {
    int tid = threadIdx.x;
    int g = tid >> 4, l = tid & 15;
    int n = blockIdx.x * 16 + g;
    size_t eoff = (size_t)n * 256 + l * 16;
    const uint4* e16 = (const uint4*)(emb + eoff);
    uint4* u16 = (uint4*)(u + eoff);
    uint4 eb0 = e16[0], eb1 = e16[1];
    if (n >= P2_) { u16[0] = eb0; u16[1] = eb1; return; }
    float tv[16], ev[16];
    {
        const uint4* t16 = (const uint4*)(t + eoff);
        unpk8(t16[0], tv); unpk8(t16[1], tv + 8);
        unpk8(eb0, ev); unpk8(eb1, ev + 8);
    }
    float m = -3.0e38f, den = 0.f, o[16];
    #pragma unroll
    for (int i = 0; i < 16; i++) o[i] = 0.f;
    auto accum = [&](const float* sv) {
        float dt = 0.f;
        #pragma unroll
        for (int i = 0; i < 16; i++) dt += tv[i] * sv[i];
        dt += __shfl_xor(dt, 1);
        dt += __shfl_xor(dt, 2);
        dt += __shfl_xor(dt, 4);
        dt += __shfl_xor(dt, 8);
        float lg = dt * 0.0625f;
        float mn = fmaxf(m, lg);
        float s0 = __expf(m - mn), s1 = __expf(lg - mn);
        den = den * s0 + s1;
        #pragma unroll
        for (int i = 0; i < 16; i++) o[i] = o[i] * s0 + s1 * sv[i];
        m = mn;
    };
    auto accum_f32 = [&](const float* base) {
        float sv[16];
        const float4* b4 = (const float4*)(base + eoff);
        #pragma unroll
        for (int i = 0; i < 4; i++) {
            float4 q = b4[i];
            sv[4 * i] = q.x; sv[4 * i + 1] = q.y; sv[4 * i + 2] = q.z; sv[4 * i + 3] = q.w;
        }
        accum(sv);
    };
    if (n < P0_)      { accum_f32(p0); accum_f32(p1); accum_f32(p2); }
    else if (n < P1_) { accum_f32(p1); accum_f32(p2); }
    else              { accum_f32(p2); }
    accum(ev);
    float inv = __builtin_amdgcn_rcpf(den);
    unsigned short h[16];
    #pragma unroll
    for (int i = 0; i < 16; i++) h[i] = f2bf(o[i] * inv);
    uint4 r0, r1;
    r0.x = h[0] | ((unsigned int)h[1] << 16);  r0.y = h[2] | ((unsigned int)h[3] << 16);
    r0.z = h[4] | ((unsigned int)h[5] << 16);  r0.w = h[6] | ((unsigned int)h[7] << 16);
    r1.x = h[8] | ((unsigned int)h[9] << 16);  r1.y = h[10] | ((unsigned int)h[11] << 16);
    r1.z = h[12] | ((unsigned int)h[13] << 16); r1.w = h[14] | ((unsigned int)h[15] << 16);
    u16[0] = r0; u16[1] = r1;
}

// ---------------- fused edge MLP v3: 256 thr, 64 edges, B direct-to-reg from frag pack ----------------
template <bool SIM>
__global__ __launch_bounds__(256)
void mfma_edge3(const unsigned short* __restrict__ srcemb, const unsigned short* __restrict__ gsrc,
                const int* __restrict__ es, const int* __restrict__ ed,
                const unsigned short* __restrict__ PkF, const float* __restrict__ b1,
                const float* __restrict__ w2, const float* __restrict__ sumb,
                float* __restrict__ a_pre, float* __restrict__ mlsc) {
    __shared__ char lds[8192];    // A: mean 4K | max 4K
    __shared__ float red[64];
    int tid = threadIdx.x, lane = tid & 63, w = tid >> 6;
    int e0 = blockIdx.x * 64;
    int arow = tid >> 2, p = tid & 3;
    int ia = es[e0 + arow], ib = ed[e0 + arow];
    const unsigned short* ra = srcemb + (size_t)ia * 256;
    const unsigned short* rb = srcemb + (size_t)ib * 256;
    const unsigned short* rg = SIM ? (gsrc + (size_t)ia * 256) : nullptr;
    int slog = p ^ ((arow >> 1) & 3);
    int abase = arow * 64 + (p << 4);
    if (tid < 64) red[tid] = 0.f;
    float simacc = 0.f;
    f32x4 acc[4][4] = {};
    // prologue: prefetch step-0 A slices into registers
    uint4 pa = *(const uint4*)(ra + (slog << 3));
    uint4 pb = *(const uint4*)(rb + (slog << 3));
    uint4 pg = make_uint4(0, 0, 0, 0);
    if (SIM) pg = *(const uint4*)(rg + (slog << 3));
    const bf16x8* BF = (const bf16x8*)PkF;   // chunk c: BF[c*64 + lane]
    for (int os = 0; os < 8; ++os) {
        // A convert + swizzled ds_write (compiler waits on pa/pb/pg)
        {
            float fa[8], fb[8];
            unpk8(pa, fa); unpk8(pb, fb);
            bf16x8 vm, vx;
            #pragma unroll
            for (int i = 0; i < 8; i++) {
                vm[i] = (short)f2bf(0.5f * (fa[i] + fb[i]));
                vx[i] = (short)f2bf(fmaxf(fa[i], fb[i]));
            }
            *(bf16x8*)(lds + abase) = vm;
            *(bf16x8*)(lds + 4096 + abase) = vx;
            if (SIM) {
                float fg[8];
                unpk8(pg, fg);
                #pragma unroll
                for (int i = 0; i < 8; i++) simacc += fg[i] * fb[i];
            }
        }
        // B half-0 fragments direct to regs (L2-resident, coalesced 1KB/wave)
        bf16x8 b0[4];
        #pragma unroll
        for (int n2 = 0; n2 < 4; ++n2)
            b0[n2] = BF[(((os << 1) << 4) + (w << 2) + n2) * 64 + lane];
        // A prefetch for step os+1 (stays in flight)
        if (os < 7) {
            int cb = ((os + 1) << 5) + (slog << 3);
            pa = *(const uint4*)(ra + cb);
            pb = *(const uint4*)(rb + cb);
            if (SIM) pg = *(const uint4*)(rg + cb);
        }
        asm volatile("s_waitcnt lgkmcnt(0)" ::: "memory");   // A ds_writes visible
        __builtin_amdgcn_s_barrier();
        __builtin_amdgcn_sched_barrier(0);
        int s = lane >> 4, r16 = lane & 15;
        {
            bf16x8 a[4];
            #pragma unroll
            for (int m2 = 0; m2 < 4; ++m2)
                a[m2] = *(const bf16x8*)(lds + lds_off(m2 * 16 + r16, s));
            __builtin_amdgcn_s_setprio(1);
            #pragma unroll
            for (int m2 = 0; m2 < 4; ++m2)
                #pragma unroll
                for (int n2 = 0; n2 < 4; ++n2)
                    acc[m2][n2] = __builtin_amdgcn_mfma_f32_16x16x32_bf16(a[m2], b0[n2], acc[m2][n2], 0, 0, 0);
            __builtin_amdgcn_s_setprio(0);
        }
        {
            bf16x8 b1r[4], a[4];
            #pragma unroll
            for (int n2 = 0; n2 < 4; ++n2)
                b1r[n2] = BF[((((os << 1) + 1) << 4) + (w << 2) + n2) * 64 + lane];
            #pragma unroll
            for (int m2 = 0; m2 < 4; ++m2)
                a[m2] = *(const bf16x8*)(lds + 4096 + lds_off(m2 * 16 + r16, s));
            __builtin_amdgcn_s_setprio(1);
            #pragma unroll
            for (int m2 = 0; m2 < 4; ++m2)
                #pragma unroll
                for (int n2 = 0; n2 < 4; ++n2)
                    acc[m2][n2] = __builtin_amdgcn_mfma_f32_16x16x32_bf16(a[m2], b1r[n2], acc[m2][n2], 0, 0, 0);
            __builtin_amdgcn_s_setprio(0);
        }
        __builtin_amdgcn_s_barrier();
        __builtin_amdgcn_sched_barrier(0);
    }
    // epilogue: layer-2 dot, reduce to per-edge scalar
    int q = lane >> 4, r16 = lane & 15;
    float b1c[4], w2c[4];
    #pragma unroll
    for (int n2 = 0; n2 < 4; ++n2) {
        int c = (w << 6) + n2 * 16 + r16;
        b1c[n2] = b1[c]; w2c[n2] = w2[c];
    }
    #pragma unroll
    for (int m2 = 0; m2 < 4; ++m2) {
        #pragma unroll
        for (int i = 0; i < 4; ++i) {
            int row = m2 * 16 + q * 4 + i;
            float ps = 0.f;
            #pragma unroll
            for (int n2 = 0; n2 < 4; ++n2) ps += tanh_fast(acc[m2][n2][i] + b1c[n2]) * w2c[n2];
            ps += __shfl_xor(ps, 1);
            ps += __shfl_xor(ps, 2);
            ps += __shfl_xor(ps, 4);
            ps += __shfl_xor(ps, 8);
            if (r16 == 0) atomicAdd(&red[row], ps);
        }
    }
    if (SIM) {
        simacc += __shfl_xor(simacc, 1);
        simacc += __shfl_xor(simacc, 2);
        if (p == 0) mlsc[e0 + arow] = sigmoid_fast(simacc + sumb[0]);
    }
    __syncthreads();
    if (tid < 64) a_pre[e0 + tid] = red[tid];
}

// ---------------- final ensemble ----------------
__global__ void k_final(const float* __restrict__ apml, const float* __restrict__ apms,
                        const float* __restrict__ mlsc, const float* __restrict__ mstr,
                        const float* __restrict__ pxtr, const int* __restrict__ index,
                        const float* __restrict__ mlb2, const float* __restrict__ msb2,
                        float* __restrict__ out) {
    int e = blockIdx.x * 256 + threadIdx.x;
    if (e >= E_) return;
    float aml = tanh_fast(apml[e] + mlb2[0]);
    float ams = tanh_fast(apms[e] + msb2[0]);
    float apx = PROXW;
    float m = fmaxf(aml, fmaxf(ams, apx));
    float wml = __expf(aml - m), wms = __expf(ams - m), wpx = __expf(apx - m);
    float inv = __builtin_amdgcn_rcpf(wml + wms + wpx);
    int idx = index[e];
    float v = (mlsc[e] * wml + mstr[idx] * wms + pxtr[idx] * wpx) * inv;
    out[e] = fminf(fmaxf(v, 0.f), 1.f);
}

__global__ void k_sentinel(float* out, int n) {
    int i = blockIdx.x * 256 + threadIdx.x;
    if (i < n) out[i] = -12345.0f;
}

// ---------------- launch ----------------
extern "C" void kernel_launch(void* const* d_in, const int* in_sizes, int n_in,
                              void* d_out, int out_size, void* d_ws, size_t ws_size,
                              hipStream_t stream) {
    const float* x     = (const float*)d_in[0];
    const int*   mp    = (const int*)d_in[1];
    const int*   edges = (const int*)d_in[2];
    const int*   index = (const int*)d_in[3];
    const float* p0    = (const float*)d_in[4];
    const float* p1    = (const float*)d_in[5];
    const float* p2    = (const float*)d_in[6];
    const float* gc1W  = (const float*)d_in[7];
    const float* gc1b  = (const float*)d_in[8];
    const float* gc2W  = (const float*)d_in[9];
    const float* gc2b  = (const float*)d_in[10];
    const float* linW  = (const float*)d_in[11];
    const float* linb  = (const float*)d_in[12];
    const float* wlin  = (const float*)d_in[13];
    const float* blin  = (const float*)d_in[14];
    const float* wq    = (const float*)d_in[15];
    const float* wk    = (const float*)d_in[16];
    const float* wv    = (const float*)d_in[17];
    const float* mlw1  = (const float*)d_in[18];
    const float* mlb1  = (const float*)d_in[19];
    const float* mlw2  = (const float*)d_in[20];
    const float* mlb2  = (const float*)d_in[21];
    const float* msw1  = (const float*)d_in[22];
    const float* msb1  = (const float*)d_in[23];
    const float* msw2  = (const float*)d_in[24];
    const float* msb2  = (const float*)d_in[25];
    const float* msdrW = (const float*)d_in[26];
    const float* msdrb = (const float*)d_in[27];
    const float* logits = (const float*)d_in[28];
    const float* mstr  = (const float*)d_in[29];
    const float* pxtr  = (const float*)d_in[30];
    float* out = (float*)d_out;

    const int* src_mp = mp;
    const int* dst_mp = mp + EMP_;
    const int* es = edges;
    const int* ed = edges + E_;

    char* ws = (char*)d_ws;
    size_t off = 0;
    auto alloc = [&](size_t bytes) -> char* {
        off = (off + 255) & ~(size_t)255;
        char* r = ws + off;
        off += bytes;
        return r;
    };
    const size_t NODE_BF = (size_t)Nn_ * 256 * 2;
    unsigned short* W0 = (unsigned short*)alloc(NODE_BF);  // xb -> gb
    unsigned short* W1 = (unsigned short*)alloc(NODE_BF);  // xw1/xw2 -> logitsb
    unsigned short* W2 = (unsigned short*)alloc(NODE_BF);  // hb -> rb
    unsigned short* W3 = (unsigned short*)alloc(NODE_BF);  // embb
    unsigned short* W4 = (unsigned short*)alloc(NODE_BF);  // tb/ub
    unsigned short* W5 = (unsigned short*)alloc(NODE_BF);  // emb2b
    int*   cnt  = (int*)alloc((size_t)Nn_ * 4);
    int*   rowp = (int*)alloc((size_t)(Nn_ + 1) * 4);
    int*   fill = (int*)alloc((size_t)Nn_ * 4);
    int*   csr  = (int*)alloc((size_t)EMP_ * 4);
    float* dinv = (float*)alloc((size_t)Nn_ * 4);
    int*   bsum = (int*)alloc(512 * 4);
    float* Mqk  = (float*)alloc(65536 * 4);
    float* W2wf = (float*)alloc(65536 * 4);
    unsigned short* gc1Wt = (unsigned short*)alloc(65536 * 2);
    unsigned short* gc2Wt = (unsigned short*)alloc(65536 * 2);
    unsigned short* MqkT  = (unsigned short*)alloc(65536 * 2);
    unsigned short* Bt512 = (unsigned short*)alloc(131072 * 2);
    unsigned short* symb  = (unsigned short*)alloc(65536 * 2);
    unsigned short* msdrWt = (unsigned short*)alloc(16384 * 2);
    unsigned short* mlPk  = (unsigned short*)alloc(131072 * 2);
    unsigned short* msPk  = (unsigned short*)alloc(131072 * 2);
    float* apml = (float*)alloc((size_t)E_ * 4);
    float* apms = (float*)alloc((size_t)E_ * 4);
    float* mlsc = (float*)alloc((size_t)E_ * 4);
    float* sumb = (float*)alloc(256);

    if (off > ws_size) {
        k_sentinel<<<(E_ + 255) / 256, 256, 0, stream>>>(out, E_);
        return;
    }

    hipMemsetAsync(cnt, 0, (size_t)Nn_ * 4, stream);
    hipMemsetAsync(fill, 0, (size_t)Nn_ * 4, stream);

    const int NB = (Nn_ + 255) / 256;
    const int EB = (EMP_ + 255) / 256;

    // input conversions + weight prep
    k_cvt<<<30000, 256, 0, stream>>>(x, W0, Nn_ * 256 / 4);
    k_transpose_cvt<<<256, 256, 0, stream>>>(gc1W, gc1Wt, 256, 256);
    k_transpose_cvt<<<256, 256, 0, stream>>>(gc2W, gc2Wt, 256, 256);
    k_transpose_cvt<<<256, 256, 0, stream>>>(msdrW, msdrWt, 64, 256);
    k_packBF<<<64, 256, 0, stream>>>(mlw1, mlPk);
    k_packBF<<<64, 256, 0, stream>>>(msw1, msPk);
    k_sym_cvt<<<256, 256, 0, stream>>>(wlin, symb);
    k_sumb<<<1, 256, 0, stream>>>(blin, sumb);
    dim3 gSmall(4, 4);
    gemm_tiled<true><<<gSmall, 256, 0, stream>>>(wq, wk, Mqk, 256, 256, 256);
    gemm_tiled<false><<<gSmall, 256, 0, stream>>>(wv, linW + 256 * 256, W2wf, 256, 256, 256);
    k_transpose_cvt<<<256, 256, 0, stream>>>(Mqk, MqkT, 256, 256);
    k_bt512<<<512, 256, 0, stream>>>(linW, W2wf, Bt512);

    // CSR
    k_count<<<EB, 256, 0, stream>>>(dst_mp, cnt, EMP_);
    k_block_reduce<<<NB, 256, 0, stream>>>(cnt, bsum, Nn_);
    k_scan_bsum<<<1, 64, 0, stream>>>(bsum, NB);
    k_scan_final<<<NB, 256, 0, stream>>>(cnt, bsum, rowp, Nn_, EMP_);
    k_fill<<<EB, 256, 0, stream>>>(src_mp, dst_mp, rowp, fill, csr, EMP_);
    k_dinv<<<NB, 256, 0, stream>>>(cnt, dinv, Nn_);

    dim3 gFull(2, (Nn_ + 127) / 128);
    dim3 gT(2, (P2_ + 127) / 128);
    const int AGG_B = (Nn_ + 3) / 4;

    // GCN layer 1
    mfma_gemm<false, false><<<gFull, 256, 0, stream>>>(W0, W0, 256, 256, gc1Wt, nullptr, W1, Nn_);
    k_agg_bf<<<AGG_B, 256, 0, stream>>>(W1, rowp, csr, dinv, gc1b, W2);
    // GCN layer 2
    mfma_gemm<false, false><<<gFull, 256, 0, stream>>>(W2, W2, 256, 256, gc2Wt, nullptr, W1, Nn_);
    k_agg_bf<<<AGG_B, 256, 0, stream>>>(W1, rowp, csr, dinv, gc2b, W3);

    // attention: t = emb @ Mqk (rows < P2), then u (16 nodes/block)
    mfma_gemm<false, false><<<gT, 256, 0, stream>>>(W3, W3, 256, 256, MqkT, nullptr, W4, P2_);
    k_attn_u2<<<Nn_ / 16, 256, 0, stream>>>(W3, W4, p0, p1, p2, W4);

    // emb2 = tanh([emb|u] @ Bt512^T + linb)
    mfma_gemm<true, true><<<gFull, 256, 0, stream>>>(W3, W4, 256, 512, Bt512, linb, W5, Nn_);

    // g = emb2 @ sym
    mfma_gemm<false, false><<<gFull, 256, 0, stream>>>(W5, W5, 256, 256, symb, nullptr, W0, Nn_);

    // r = tanh(logits @ msdrW + msdrb)
    k_cvt<<<7500, 256, 0, stream>>>(logits, W1, Nn_ * 64 / 4);
    mfma_gemm<true, true><<<gFull, 256, 0, stream>>>(W1, W1, 64, 64, msdrWt, msdrb, W2, Nn_);

    // edge MLPs (+fused bilinear sim in the ml pass)
    mfma_edge3<true><<<E_ / 64, 256, 0, stream>>>(W5, W0, es, ed, mlPk, mlb1, mlw2, sumb, apml, mlsc);
    mfma_edge3<false><<<E_ / 64, 256, 0, stream>>>(W2, nullptr, es, ed, msPk, msb1, msw2, sumb, apms, nullptr);

    // final ensemble
    k_final<<<(E_ + 255) / 256, 256, 0, stream>>>(apml, apms, mlsc, mstr, pxtr, index, mlb2, msb2, out);
}